// Round 9
// baseline (223.958 us; speedup 1.0000x reference)
//
#include <hip/hip_runtime.h>

typedef float f4 __attribute__((ext_vector_type(4)));

#define LOG2E 1.4426950408889634f
#define LN2   0.6931471805599453

// B blocks x 128 threads. Wave 0: forward recursion t=0..m-1; wave 1: backward
// recursion t=len-1..m; Z = sum_k A_m[k]*B_m[k]. Lane k owns state k; per-step
// broadcast via v_readlane. The 64 transition factors live in 16 NAMED float4
// variables (e0..e15) so they are guaranteed VGPR-resident (R1-R7 kept them in
// scratch -- the constant ~830cy/step stall). eT pre-scaled by 2^-7 (exact);
// power-of-2 renorm once per 4 steps; exact integer scale bookkeeping.

#define MVG(r, ev) do { \
    float q0 = __uint_as_float(__builtin_amdgcn_readlane(uu, 4*(r) + 0)); \
    float q1 = __uint_as_float(__builtin_amdgcn_readlane(uu, 4*(r) + 1)); \
    float q2 = __uint_as_float(__builtin_amdgcn_readlane(uu, 4*(r) + 2)); \
    float q3 = __uint_as_float(__builtin_amdgcn_readlane(uu, 4*(r) + 3)); \
    s0 = fmaf(q0, (ev).x, s0); \
    s1 = fmaf(q1, (ev).y, s1); \
    s2 = fmaf(q2, (ev).z, s2); \
    s3 = fmaf(q3, (ev).w, s3); \
} while (0)

#define MATVEC(Sv) do { \
    const unsigned uu = __float_as_uint(u); \
    float s0 = 0.f, s1 = 0.f, s2 = 0.f, s3 = 0.f; \
    MVG(0,e0);  MVG(1,e1);  MVG(2,e2);  MVG(3,e3); \
    MVG(4,e4);  MVG(5,e5);  MVG(6,e6);  MVG(7,e7); \
    MVG(8,e8);  MVG(9,e9);  MVG(10,e10); MVG(11,e11); \
    MVG(12,e12); MVG(13,e13); MVG(14,e14); MVG(15,e15); \
    (Sv) = (s0 + s1) + (s2 + s3); \
} while (0)

#define STEPL(lv) do { \
    float el = __builtin_amdgcn_exp2f((lv) * LOG2E); \
    float Sv; MATVEC(Sv); \
    u = Sv * el; \
} while (0)

#define RENORM() do { \
    unsigned E = __builtin_amdgcn_readfirstlane(__float_as_uint(u)) >> 23; \
    u *= __uint_as_float((254u - E) << 23); \
    M2i += (int)E - 127; \
} while (0)

// load one f4 of prescaled exp(T): fwd row-major (j*L + c), bwd col-major (c*L + j)
#define LOADE_F(r, ev) do { \
    (ev).x = __builtin_amdgcn_exp2f(Tm[j*L + 4*(r) + 0] * LOG2E) * SC; \
    (ev).y = __builtin_amdgcn_exp2f(Tm[j*L + 4*(r) + 1] * LOG2E) * SC; \
    (ev).z = __builtin_amdgcn_exp2f(Tm[j*L + 4*(r) + 2] * LOG2E) * SC; \
    (ev).w = __builtin_amdgcn_exp2f(Tm[j*L + 4*(r) + 3] * LOG2E) * SC; \
} while (0)
#define LOADE_B(r, ev) do { \
    (ev).x = __builtin_amdgcn_exp2f(Tm[(4*(r) + 0)*L + j] * LOG2E) * SC; \
    (ev).y = __builtin_amdgcn_exp2f(Tm[(4*(r) + 1)*L + j] * LOG2E) * SC; \
    (ev).z = __builtin_amdgcn_exp2f(Tm[(4*(r) + 2)*L + j] * LOG2E) * SC; \
    (ev).w = __builtin_amdgcn_exp2f(Tm[(4*(r) + 3)*L + j] * LOG2E) * SC; \
} while (0)

__global__ __launch_bounds__(128, 1)
void crf_nll_kernel(const float* __restrict__ logits,
                    const float* __restrict__ Tm,
                    const int* __restrict__ labels,
                    const int* __restrict__ mask_g,
                    float* __restrict__ out,
                    int B, int S)
{
    const int b   = blockIdx.x;
    const int tid = threadIdx.x;
    const int w   = tid >> 6;          // 0 = forward, 1 = backward
    const int j   = tid & 63;
    constexpr int L = 66, START = 64, END = 65;
    const float SC = 0.0078125f;       // 2^-7, exact

    __shared__ __align__(16) float exch[64];
    __shared__ int   redI[2];
    __shared__ float redF[2];
    __shared__ int   redM;

    const float* lg  = logits + (size_t)b * S * 64;
    const int*   lab = labels + (size_t)b * S;
    const int*   msk = mask_g + (size_t)b * S;

    // ---------- prephase: len + full gold score (unary gather + transitions)
    int   lensum = 0;
    float gsum   = 0.0f;
    for (int t0 = tid; t0 < S; t0 += 128) {
        if (msk[t0]) {
            ++lensum;
            int lc = lab[t0];
            float ga = lg[(size_t)t0 * 64 + lc];
            if (t0 > 0) ga += Tm[lc * L + lab[t0 - 1]];
            gsum += ga;
        }
    }
    #pragma unroll
    for (int off = 32; off; off >>= 1) {
        lensum += __shfl_xor(lensum, off);
        gsum   += __shfl_xor(gsum, off);
    }
    if (j == 0) { redI[w] = lensum; redF[w] = gsum; }

    __syncthreads();
    const int   len   = redI[0] + redI[1];
    const float goldp = redF[0] + redF[1];
    const int   m_mid = (len + 1) >> 1;

    float u;
    int   M2i = 0;          // exact log2-scale accumulator

    if (w == 0) {
        // ---------------- forward: A_1 init, then steps t = 1 .. tmax
        f4 e0,e1,e2,e3,e4,e5,e6,e7,e8,e9,e10,e11,e12,e13,e14,e15;
        LOADE_F(0,e0);  LOADE_F(1,e1);  LOADE_F(2,e2);  LOADE_F(3,e3);
        LOADE_F(4,e4);  LOADE_F(5,e5);  LOADE_F(6,e6);  LOADE_F(7,e7);
        LOADE_F(8,e8);  LOADE_F(9,e9);  LOADE_F(10,e10); LOADE_F(11,e11);
        LOADE_F(12,e12); LOADE_F(13,e13); LOADE_F(14,e14); LOADE_F(15,e15);

        const int tmax = m_mid - 1;
        u = __builtin_amdgcn_exp2f((lg[j] + Tm[j * L + START]) * LOG2E);

        #define LGF(t) lg[(size_t)(((t) > tmax) ? tmax : (((t) < 1) ? 1 : (t))) * 64 + j]
        float la0 = LGF(1), la1 = LGF(2), la2 = LGF(3), la3 = LGF(4);
        float lb0 = LGF(5), lb1 = LGF(6), lb2 = LGF(7), lb3 = LGF(8);
        float nx0, nx1, nx2, nx3;
        int base = 1;
        #pragma clang loop unroll(disable)
        for (; base + 7 <= tmax; base += 4) {
            nx0 = LGF(base + 8); nx1 = LGF(base + 9);
            nx2 = LGF(base + 10); nx3 = LGF(base + 11);
            STEPL(la0); STEPL(la1); STEPL(la2); STEPL(la3);
            RENORM();
            la0 = lb0; la1 = lb1; la2 = lb2; la3 = lb3;
            lb0 = nx0; lb1 = nx1; lb2 = nx2; lb3 = nx3;
        }
        int rem = tmax - base + 1;                  // 0..7
        if (rem > 0) STEPL(la0);
        if (rem > 1) STEPL(la1);
        if (rem > 2) STEPL(la2);
        if (rem > 3) STEPL(la3);
        if (rem > 4) STEPL(lb0);
        if (rem > 5) STEPL(lb1);
        if (rem > 6) STEPL(lb2);
        M2i += 7 * tmax;                            // undo 2^-7 pre-scale
        #undef LGF
    } else {
        // ---------------- backward: B_len init (+ logit_{len-1}); n_b steps,
        // first n_b-1 carry a logit, the last does not.
        f4 e0,e1,e2,e3,e4,e5,e6,e7,e8,e9,e10,e11,e12,e13,e14,e15;
        LOADE_B(0,e0);  LOADE_B(1,e1);  LOADE_B(2,e2);  LOADE_B(3,e3);
        LOADE_B(4,e4);  LOADE_B(5,e5);  LOADE_B(6,e6);  LOADE_B(7,e7);
        LOADE_B(8,e8);  LOADE_B(9,e9);  LOADE_B(10,e10); LOADE_B(11,e11);
        LOADE_B(12,e12); LOADE_B(13,e13); LOADE_B(14,e14); LOADE_B(15,e15);

        const int n_b  = len - m_mid;
        const int n_el = n_b - 1;
        float initl = (n_b > 0) ? lg[(size_t)(len - 1) * 64 + j] : 0.0f;
        u = __builtin_amdgcn_exp2f((Tm[END * L + j] + initl) * LOG2E);

        #define LGB(i) lg[(size_t)(((len - 2 - (i)) < 0) ? 0 : (len - 2 - (i))) * 64 + j]
        float la0 = LGB(0), la1 = LGB(1), la2 = LGB(2), la3 = LGB(3);
        float lb0 = LGB(4), lb1 = LGB(5), lb2 = LGB(6), lb3 = LGB(7);
        float nx0, nx1, nx2, nx3;
        int base = 0;
        #pragma clang loop unroll(disable)
        for (; base + 8 <= n_el; base += 4) {
            nx0 = LGB(base + 8); nx1 = LGB(base + 9);
            nx2 = LGB(base + 10); nx3 = LGB(base + 11);
            STEPL(la0); STEPL(la1); STEPL(la2); STEPL(la3);
            RENORM();
            la0 = lb0; la1 = lb1; la2 = lb2; la3 = lb3;
            lb0 = nx0; lb1 = nx1; lb2 = nx2; lb3 = nx3;
        }
        int rem = n_el - base;                      // 0..7
        if (rem > 0) STEPL(la0);
        if (rem > 1) STEPL(la1);
        if (rem > 2) STEPL(la2);
        if (rem > 3) STEPL(la3);
        if (rem > 4) STEPL(lb0);
        if (rem > 5) STEPL(lb1);
        if (rem > 6) STEPL(lb2);
        if (n_b >= 1) { float Sv; MATVEC(Sv); u = Sv; }   // final step, no logit
        M2i += 7 * n_b;                             // undo 2^-7 pre-scale
        #undef LGB
    }

    // ---------- combine: Z = ln2 * (M2f + M2b + log2( sum_k uf[k]*ub[k] ))
    if (w == 1) {
        exch[j] = u;
        if (j == 0) redM = M2i;
    }
    __syncthreads();
    if (w == 0) {
        float v = u * exch[j];
        #pragma unroll
        for (int off = 32; off; off >>= 1) v += __shfl_xor(v, off);
        if (j == 0) {
            int    Msum = M2i + redM;
            double Z    = ((double)Msum + (double)__builtin_amdgcn_logf(v)) * LN2;
            int lab0 = lab[0];
            int labl = lab[len - 1];
            float goldall = goldp + Tm[lab0 * L + START] + Tm[END * L + labl];
            out[b] = (float)(Z - (double)goldall);
        }
    }
}

extern "C" void kernel_launch(void* const* d_in, const int* in_sizes, int n_in,
                              void* d_out, int out_size, void* d_ws, size_t ws_size,
                              hipStream_t stream) {
    const float* logits = (const float*)d_in[0];
    const float* Tm     = (const float*)d_in[1];
    const int*   labels = (const int*)d_in[2];
    const int*   mask   = (const int*)d_in[3];
    float*       out    = (float*)d_out;

    const int B = out_size;                 // 512
    const int S = in_sizes[2] / B;          // 1024

    crf_nll_kernel<<<dim3(B), dim3(128), 0, stream>>>(logits, Tm, labels, mask, out, B, S);
}